// Round 3
// baseline (1608.069 us; speedup 1.0000x reference)
//
#include <hip/hip_runtime.h>
#include <hip/hip_bf16.h>
#include <math.h>

using bf = __hip_bfloat16;
typedef unsigned short u16;
typedef __attribute__((ext_vector_type(8))) unsigned short us8;
typedef __attribute__((ext_vector_type(8))) __bf16 bf16x8;
typedef __attribute__((ext_vector_type(4))) float f32x4;

static constexpr int kC    = 384;
static constexpr int kHid  = 1536;
static constexpr int kHeads= 12;
static constexpr int kN    = 49;     // tokens per window
static constexpr float kScale = 0.17677669529663687f;  // 32^-0.5
static constexpr int kChunkWins = 512;                  // windows per chunk
static constexpr int kChunkRows = kChunkWins * kN;      // 25088
static constexpr int kPlane = kChunkWins * kHeads * kN * 32; // 9,633,792 elems

__device__ __forceinline__ float b2f(bf v){ return __bfloat162float(v); }
__device__ __forceinline__ bf    f2b(float v){ return __float2bfloat16(v); }

// ---------------- weight transpose: out[n*K+k] = bf16(in[k*N+n]) ----------
__global__ void tr_k(const float* __restrict__ in, bf* __restrict__ out, int K, int N){
  int i = blockIdx.x*256 + threadIdx.x;
  if (i < K*N){ int k = i / N, n = i - k*N; out[(size_t)n*K + k] = f2b(in[i]); }
}

// ---- LayerNorm. GATHER=1: fused shift + window partition ----
template<int GATHER>
__global__ __launch_bounds__(256) void ln_k(const float* __restrict__ x, const float* __restrict__ g,
                                            const float* __restrict__ be, bf* __restrict__ out,
                                            int winbase){
  int wv = threadIdx.x >> 6, lane = threadIdx.x & 63;
  int lr = blockIdx.x*4 + wv;              // local row in chunk [0,25088)
  const float* src;
  if constexpr (GATHER){
    int win = lr / kN, n = lr - win*kN;
    int gw = winbase + win;
    int b = gw >> 6, rem = gw & 63, wh = rem >> 3, ww = rem & 7;
    int ih = n / 7, iw = n - ih*7;
    int h0 = (wh*7 + ih + 3) % 56;
    int w0 = (ww*7 + iw + 3) % 56;
    src = x + ((size_t)b*3136 + h0*56 + w0) * kC;
  } else {
    src = x + (size_t)lr * kC;
  }
  float vals[6]; float s = 0.f, sq = 0.f;
  #pragma unroll
  for (int j = 0; j < 6; ++j){ float f = src[j*64 + lane]; vals[j] = f; s += f; sq += f*f; }
  #pragma unroll
  for (int o = 32; o > 0; o >>= 1){ s += __shfl_down(s, o); sq += __shfl_down(sq, o); }
  s = __shfl(s, 0); sq = __shfl(sq, 0);
  float mean = s * (1.f/384.f);
  float var  = sq * (1.f/384.f) - mean*mean;
  float rstd = rsqrtf(var + 1e-5f);
  bf* dst = out + (size_t)lr * kC;
  #pragma unroll
  for (int j = 0; j < 6; ++j){
    int c = j*64 + lane;
    dst[c] = f2b((vals[j]-mean)*rstd*g[c] + be[c]);
  }
}

// --------------------- tiled bf16 MFMA GEMM, 128x128 ----------------------
// A[M,K](bf16) @ Wt[N,K](bf16)^T + bias(f32). Epilogues:
//  0: qkv scatter into q/k/v planes (q scaled), bf16
//  1: proj: + window-reverse/unshift residual (f32 x), writes x1(f32) into fo
//  2: fc1: gelu(exact), bf16, row stride kHid
//  3: fc2: + residual (f32 rows == fo), f32, row stride kC
template<int EPI>
__global__ __launch_bounds__(256) void gemm_k(const bf* __restrict__ A, const bf* __restrict__ Wt,
                                              const float* __restrict__ bias, int K,
                                              bf* o0, bf* o1, bf* o2,
                                              float* fo, const float* res, int aux){
  __shared__ u16 sA[128*40];
  __shared__ u16 sB[128*40];
  int t = threadIdx.x;
  int bm = blockIdx.x << 7, bn = blockIdx.y << 7;
  int lrow = t >> 2, lcol = (t & 3) * 8;
  const u16* Ag = (const u16*)A  + (size_t)(bm + lrow)*K + lcol;
  const u16* Bg = (const u16*)Wt + (size_t)(bn + lrow)*K + lcol;
  size_t half = (size_t)64 * K;
  u16* wa0 = &sA[lrow*40 + lcol]; u16* wa1 = &sA[(lrow+64)*40 + lcol];
  u16* wb0 = &sB[lrow*40 + lcol]; u16* wb1 = &sB[(lrow+64)*40 + lcol];
  int lane = t & 63, wv = t >> 6, wr = wv >> 1, wc = wv & 1, lr = lane & 15, lk = lane >> 4;
  const u16* ra = &sA[(wr*64 + lr)*40 + lk*8];
  const u16* rb = &sB[(wc*64 + lr)*40 + lk*8];
  f32x4 acc[4][4];
  #pragma unroll
  for (int i = 0; i < 4; ++i)
    #pragma unroll
    for (int j = 0; j < 4; ++j) acc[i][j] = (f32x4){0.f,0.f,0.f,0.f};

  for (int kk = 0; kk < K; kk += 32){
    us8 va0 = *(const us8*)Ag;
    us8 va1 = *(const us8*)(Ag + half);
    us8 vb0 = *(const us8*)Bg;
    us8 vb1 = *(const us8*)(Bg + half);
    Ag += 32; Bg += 32;
    __syncthreads();
    *(us8*)wa0 = va0; *(us8*)wa1 = va1;
    *(us8*)wb0 = vb0; *(us8*)wb1 = vb1;
    __syncthreads();
    bf16x8 af[4], bfr[4];
    #pragma unroll
    for (int mi = 0; mi < 4; ++mi) af[mi]  = __builtin_bit_cast(bf16x8, *(const us8*)(ra + mi*640));
    #pragma unroll
    for (int ni = 0; ni < 4; ++ni) bfr[ni] = __builtin_bit_cast(bf16x8, *(const us8*)(rb + ni*640));
    #pragma unroll
    for (int mi = 0; mi < 4; ++mi)
      #pragma unroll
      for (int ni = 0; ni < 4; ++ni)
        acc[mi][ni] = __builtin_amdgcn_mfma_f32_16x16x32_bf16(af[mi], bfr[ni], acc[mi][ni], 0, 0, 0);
  }

  #pragma unroll
  for (int ni = 0; ni < 4; ++ni){
    int col = bn + wc*64 + ni*16 + lr;
    float bs = bias[col];
    #pragma unroll
    for (int mi = 0; mi < 4; ++mi){
      #pragma unroll
      for (int r = 0; r < 4; ++r){
        int row = bm + wr*64 + mi*16 + lk*4 + r;
        float v = acc[mi][ni][r] + bs;
        if constexpr (EPI == 0){
          int which = col / kC; int cc = col - which*kC; int hd = cc >> 5, d = cc & 31;
          int win = row / kN, n = row - win*kN;
          bf* dst = which == 0 ? o0 : (which == 1 ? o1 : o2);
          if (which == 0) v *= kScale;
          dst[((size_t)(win*kHeads + hd))*(kN*32) + n*32 + d] = f2b(v);
        } else if constexpr (EPI == 1){
          int win = row / kN, n = row - win*kN;
          int gw = aux + win;
          int b = gw >> 6, rem = gw & 63, wh = rem >> 3, ww = rem & 7;
          int ih = n / 7, iw = n - ih*7;
          int h0 = (wh*7 + ih + 3) % 56;
          int w0 = (ww*7 + iw + 3) % 56;
          size_t idx = ((size_t)b*3136 + h0*56 + w0)*kC + col;
          fo[idx] = v + res[idx];
        } else if constexpr (EPI == 2){
          v = 0.5f * v * (1.f + erff(v * 0.70710678118654752f));
          o0[(size_t)row*kHid + col] = f2b(v);
        } else {
          size_t idx = (size_t)row*kC + col;
          fo[idx] = v + res[idx];
        }
      }
    }
  }
}

// --------------------------- window attention -----------------------------
// one wave per (window, head); K,V and the score row live in LDS
__global__ __launch_bounds__(64) void attn_k(const bf* __restrict__ q, const bf* __restrict__ kkk,
                                             const bf* __restrict__ vvv, const float* __restrict__ relb,
                                             bf* __restrict__ out){
  __shared__ float ks[kN*32], vs[kN*32], ps[kN*52];
  int bid = blockIdx.x, lw = bid / kHeads, h = bid - lw*kHeads;
  const bf* qp = q   + (size_t)bid * (kN*32);
  const bf* kp = kkk + (size_t)bid * (kN*32);
  const bf* vp = vvv + (size_t)bid * (kN*32);
  int t = threadIdx.x;
  for (int i = t; i < kN*32; i += 64){ ks[i] = b2f(kp[i]); vs[i] = b2f(vp[i]); }
  __syncthreads();
  if (t < kN){
    float qr[32];
    #pragma unroll
    for (int d = 0; d < 32; ++d) qr[d] = b2f(qp[t*32 + d]);
    int ih = t / 7, iw = t - ih*7;
    float* prow = &ps[t*52];
    for (int m = 0; m < kN; ++m){
      float a = 0.f;
      #pragma unroll
      for (int d = 0; d < 32; ++d) a += qr[d] * ks[m*32 + d];
      int kh = m / 7, kw = m - kh*7;
      a += relb[((ih - kh + 6)*13 + (iw - kw + 6))*kHeads + h];
      prow[m] = a;
    }
    float mx = -1e30f;
    for (int m = 0; m < kN; ++m) mx = fmaxf(mx, prow[m]);
    float sum = 0.f;
    for (int m = 0; m < kN; ++m){ float e = expf(prow[m] - mx); prow[m] = e; sum += e; }
    float inv = 1.f / sum;
    float o[32];
    #pragma unroll
    for (int d = 0; d < 32; ++d) o[d] = 0.f;
    for (int m = 0; m < kN; ++m){
      float p = prow[m];
      #pragma unroll
      for (int d = 0; d < 32; ++d) o[d] += p * vs[m*32 + d];
    }
    bf* op = out + ((size_t)lw*kN + t)*kC + h*32;
    #pragma unroll
    for (int d = 0; d < 32; ++d) op[d] = f2b(o[d] * inv);
  }
}

extern "C" void kernel_launch(void* const* d_in, const int* in_sizes, int n_in,
                              void* d_out, int out_size, void* d_ws, size_t ws_size,
                              hipStream_t stream){
  (void)in_sizes; (void)n_in; (void)out_size; (void)ws_size;
  const float* x     = (const float*)d_in[0];
  const float* n1g   = (const float*)d_in[1];
  const float* n1b   = (const float*)d_in[2];
  const float* qkvw  = (const float*)d_in[3];
  const float* qkvb  = (const float*)d_in[4];
  const float* relb  = (const float*)d_in[5];
  const float* projw = (const float*)d_in[6];
  const float* projb = (const float*)d_in[7];
  const float* n2g   = (const float*)d_in[8];
  const float* n2b   = (const float*)d_in[9];
  const float* fc1w  = (const float*)d_in[10];
  const float* fc1b  = (const float*)d_in[11];
  const float* fc2w  = (const float*)d_in[12];
  const float* fc2b  = (const float*)d_in[13];
  float* out = (float*)d_out;

  char* w = (char*)d_ws;
  const size_t WINB  = 19267584;   // 25088*384*2
  const size_t BIGB  = 77070336;   // 25088*1536*2 (qkv planes / mlp hidden)
  bf* winbuf = (bf*)w;             // ln output; also reused as attention output
  bf* big    = (bf*)(w + WINB);
  bf* wts    = (bf*)(w + WINB + BIGB);
  bf* qkvwt  = wts;                 // [1152][384]
  bf* projwt = qkvwt + 442368;      // [384][384]
  bf* fc1wt  = projwt + 147456;     // [1536][384]
  bf* fc2wt  = fc1wt + 589824;      // [384][1536]
  bf* qb = big; bf* kb = big + kPlane; bf* vb = big + 2*(size_t)kPlane;

  tr_k<<<dim3((442368+255)/256), 256, 0, stream>>>(qkvw,  qkvwt, 384, 1152);
  tr_k<<<dim3((147456+255)/256), 256, 0, stream>>>(projw, projwt, 384, 384);
  tr_k<<<dim3((589824+255)/256), 256, 0, stream>>>(fc1w,  fc1wt, 384, 1536);
  tr_k<<<dim3((589824+255)/256), 256, 0, stream>>>(fc2w,  fc2wt, 1536, 384);

  // attention path, 4 window chunks; proj epilogue writes x1 = x + attn (f32) into d_out
  for (int c = 0; c < 4; ++c){
    int winbase = c * kChunkWins;
    ln_k<1><<<kChunkRows/4, 256, 0, stream>>>(x, n1g, n1b, winbuf, winbase);
    gemm_k<0><<<dim3(kChunkRows/128, 9), 256, 0, stream>>>(winbuf, qkvwt, qkvb, 384,
                                                           qb, kb, vb, nullptr, nullptr, 0);
    attn_k<<<kChunkWins*kHeads, 64, 0, stream>>>(qb, kb, vb, relb, winbuf);
    gemm_k<1><<<dim3(kChunkRows/128, 3), 256, 0, stream>>>(winbuf, projwt, projb, 384,
                                                           nullptr, nullptr, nullptr, out, x, winbase);
  }
  // MLP path on x1 rows (f32, in d_out), 4 row chunks; fc2 adds residual in place
  for (int c = 0; c < 4; ++c){
    float* xr = out + (size_t)c * kChunkRows * kC;
    ln_k<0><<<kChunkRows/4, 256, 0, stream>>>(xr, n2g, n2b, winbuf, 0);
    gemm_k<2><<<dim3(kChunkRows/128, 12), 256, 0, stream>>>(winbuf, fc1wt, fc1b, 384,
                                                            big, nullptr, nullptr, nullptr, nullptr, 0);
    gemm_k<3><<<dim3(kChunkRows/128, 3), 256, 0, stream>>>(big, fc2wt, fc2b, 1536,
                                                           nullptr, nullptr, nullptr, xr, xr, 0);
  }
}

// Round 4
// 1542.519 us; speedup vs baseline: 1.0425x; 1.0425x over previous
//
#include <hip/hip_runtime.h>
#include <hip/hip_bf16.h>
#include <math.h>

using bf = __hip_bfloat16;
typedef unsigned short u16;
typedef __attribute__((ext_vector_type(8))) unsigned short us8;
typedef __attribute__((ext_vector_type(8))) __bf16 bf16x8;
typedef __attribute__((ext_vector_type(4))) float f32x4;

static constexpr int kC    = 384;
static constexpr int kHid  = 1536;
static constexpr int kHeads= 12;
static constexpr int kN    = 49;     // tokens per window
static constexpr float kScale = 0.17677669529663687f;  // 32^-0.5
static constexpr int kChunkWins = 512;                  // windows per chunk
static constexpr int kChunkRows = kChunkWins * kN;      // 25088
static constexpr int kPlane = kChunkWins * kHeads * kN * 32; // 9,633,792 elems

__device__ __forceinline__ float b2f(bf v){ return __bfloat162float(v); }
__device__ __forceinline__ bf    f2b(float v){ return __float2bfloat16(v); }

__device__ __forceinline__ void gload16(const void* g, void* l){
  __builtin_amdgcn_global_load_lds(
      (const __attribute__((address_space(1))) void*)g,
      (__attribute__((address_space(3))) void*)l, 16, 0, 0);
}

// ---------------- weight transpose: out[n*K+k] = bf16(in[k*N+n]) ----------
__global__ void tr_k(const float* __restrict__ in, bf* __restrict__ out, int K, int N){
  int i = blockIdx.x*256 + threadIdx.x;
  if (i < K*N){ int k = i / N, n = i - k*N; out[(size_t)n*K + k] = f2b(in[i]); }
}

// ---- LayerNorm. GATHER=1: fused shift + window partition ----
template<int GATHER>
__global__ __launch_bounds__(256) void ln_k(const float* __restrict__ x, const float* __restrict__ g,
                                            const float* __restrict__ be, bf* __restrict__ out,
                                            int winbase){
  int wv = threadIdx.x >> 6, lane = threadIdx.x & 63;
  int lr = blockIdx.x*4 + wv;              // local row in chunk [0,25088)
  const float* src;
  if constexpr (GATHER){
    int win = lr / kN, n = lr - win*kN;
    int gw = winbase + win;
    int b = gw >> 6, rem = gw & 63, wh = rem >> 3, ww = rem & 7;
    int ih = n / 7, iw = n - ih*7;
    int h0 = (wh*7 + ih + 3) % 56;
    int w0 = (ww*7 + iw + 3) % 56;
    src = x + ((size_t)b*3136 + h0*56 + w0) * kC;
  } else {
    src = x + (size_t)lr * kC;
  }
  float vals[6]; float s = 0.f, sq = 0.f;
  #pragma unroll
  for (int j = 0; j < 6; ++j){ float f = src[j*64 + lane]; vals[j] = f; s += f; sq += f*f; }
  #pragma unroll
  for (int o = 32; o > 0; o >>= 1){ s += __shfl_down(s, o); sq += __shfl_down(sq, o); }
  s = __shfl(s, 0); sq = __shfl(sq, 0);
  float mean = s * (1.f/384.f);
  float var  = sq * (1.f/384.f) - mean*mean;
  float rstd = rsqrtf(var + 1e-5f);
  bf* dst = out + (size_t)lr * kC;
  #pragma unroll
  for (int j = 0; j < 6; ++j){
    int c = j*64 + lane;
    dst[c] = f2b((vals[j]-mean)*rstd*g[c] + be[c]);
  }
}

// ------------- m97-style tiled bf16 MFMA GEMM, 128x128, BK=32 -------------
// A[M,K](bf16) @ Wt[N,K](bf16)^T + bias(f32). global_load_lds staging,
// linear LDS [128][32], bijective XCD swizzle, bm-major per XCD.
// Epilogues: 0 qkv-scatter / 1 proj+unshift+residual(f32) / 2 gelu / 3 +res(f32)
template<int EPI>
__global__ __launch_bounds__(256) void gemm_k(const bf* __restrict__ A, const bf* __restrict__ Wt,
                                              const float* __restrict__ bias, int K, int nbn,
                                              bf* o0, bf* o1, bf* o2,
                                              float* fo, const float* res, int aux){
  __shared__ u16 sA[128*32];
  __shared__ u16 sB[128*32];
  // bijective XCD swizzle (m204)
  int nwg = gridDim.x, id = blockIdx.x;
  int q = nwg >> 3, r = nwg & 7, xcd = id & 7, off = id >> 3;
  int swz = (xcd < r ? xcd*(q+1) : r*(q+1) + (xcd-r)*q) + off;
  int bm = (swz / nbn) << 7, bn = (swz % nbn) << 7;

  int t = threadIdx.x, lane = t & 63, wv = t >> 6;
  // staging: wave wv owns rows [wv*32, wv*32+32) of both tiles, 2 loads each
  const u16* Ag = (const u16*)A  + (size_t)(bm + wv*32 + (lane >> 2))*K + (lane & 3)*8;
  const u16* Bg = (const u16*)Wt + (size_t)(bn + wv*32 + (lane >> 2))*K + (lane & 3)*8;
  size_t rstep = (size_t)16 * K;            // 16 rows
  u16* lA0 = &sA[(wv*32)*32];  u16* lA1 = &sA[(wv*32 + 16)*32];
  u16* lB0 = &sB[(wv*32)*32];  u16* lB1 = &sB[(wv*32 + 16)*32];

  int wr = wv >> 1, wc = wv & 1, lr = lane & 15, lk = lane >> 4;
  const u16* ra = &sA[(wr*64 + lr)*32 + lk*8];
  const u16* rb = &sB[(wc*64 + lr)*32 + lk*8];
  f32x4 acc[4][4];
  #pragma unroll
  for (int i = 0; i < 4; ++i)
    #pragma unroll
    for (int j = 0; j < 4; ++j) acc[i][j] = (f32x4){0.f,0.f,0.f,0.f};

  for (int kk = 0; kk < K; kk += 32){
    gload16(Ag, lA0); gload16(Ag + rstep, lA1);
    gload16(Bg, lB0); gload16(Bg + rstep, lB1);
    Ag += 32; Bg += 32;
    asm volatile("s_waitcnt vmcnt(0)" ::: "memory");
    __syncthreads();
    bf16x8 af[4], bfr[4];
    #pragma unroll
    for (int mi = 0; mi < 4; ++mi) af[mi]  = __builtin_bit_cast(bf16x8, *(const us8*)(ra + mi*512));
    #pragma unroll
    for (int ni = 0; ni < 4; ++ni) bfr[ni] = __builtin_bit_cast(bf16x8, *(const us8*)(rb + ni*512));
    #pragma unroll
    for (int mi = 0; mi < 4; ++mi)
      #pragma unroll
      for (int ni = 0; ni < 4; ++ni)
        acc[mi][ni] = __builtin_amdgcn_mfma_f32_16x16x32_bf16(af[mi], bfr[ni], acc[mi][ni], 0, 0, 0);
    __syncthreads();
  }

  #pragma unroll
  for (int ni = 0; ni < 4; ++ni){
    int col = bn + wc*64 + ni*16 + lr;
    float bs = bias[col];
    #pragma unroll
    for (int mi = 0; mi < 4; ++mi){
      #pragma unroll
      for (int r2 = 0; r2 < 4; ++r2){
        int row = bm + wr*64 + mi*16 + lk*4 + r2;
        float v = acc[mi][ni][r2] + bs;
        if constexpr (EPI == 0){
          int which = col / kC; int cc = col - which*kC; int hd = cc >> 5, d = cc & 31;
          int win = row / kN, n = row - win*kN;
          bf* dst = which == 0 ? o0 : (which == 1 ? o1 : o2);
          if (which == 0) v *= kScale;
          dst[((size_t)(win*kHeads + hd))*(kN*32) + n*32 + d] = f2b(v);
        } else if constexpr (EPI == 1){
          int win = row / kN, n = row - win*kN;
          int gw = aux + win;
          int b = gw >> 6, rem = gw & 63, wh = rem >> 3, ww = rem & 7;
          int ih = n / 7, iw = n - ih*7;
          int h0 = (wh*7 + ih + 3) % 56;
          int w0 = (ww*7 + iw + 3) % 56;
          size_t idx = ((size_t)b*3136 + h0*56 + w0)*kC + col;
          fo[idx] = v + res[idx];
        } else if constexpr (EPI == 2){
          v = 0.5f * v * (1.f + erff(v * 0.70710678118654752f));
          o0[(size_t)row*kHid + col] = f2b(v);
        } else {
          size_t idx = (size_t)row*kC + col;
          fo[idx] = v + res[idx];
        }
      }
    }
  }
}

// --------------------------- window attention -----------------------------
__global__ __launch_bounds__(64) void attn_k(const bf* __restrict__ q, const bf* __restrict__ kkk,
                                             const bf* __restrict__ vvv, const float* __restrict__ relb,
                                             bf* __restrict__ out){
  __shared__ float ks[kN*32], vs[kN*32], ps[kN*52];
  int bid = blockIdx.x, lw = bid / kHeads, h = bid - lw*kHeads;
  const bf* qp = q   + (size_t)bid * (kN*32);
  const bf* kp = kkk + (size_t)bid * (kN*32);
  const bf* vp = vvv + (size_t)bid * (kN*32);
  int t = threadIdx.x;
  for (int i = t; i < kN*32; i += 64){ ks[i] = b2f(kp[i]); vs[i] = b2f(vp[i]); }
  __syncthreads();
  if (t < kN){
    float qr[32];
    #pragma unroll
    for (int d = 0; d < 32; ++d) qr[d] = b2f(qp[t*32 + d]);
    int ih = t / 7, iw = t - ih*7;
    float* prow = &ps[t*52];
    for (int m = 0; m < kN; ++m){
      float a = 0.f;
      #pragma unroll
      for (int d = 0; d < 32; ++d) a += qr[d] * ks[m*32 + d];
      int kh = m / 7, kw = m - kh*7;
      a += relb[((ih - kh + 6)*13 + (iw - kw + 6))*kHeads + h];
      prow[m] = a;
    }
    float mx = -1e30f;
    for (int m = 0; m < kN; ++m) mx = fmaxf(mx, prow[m]);
    float sum = 0.f;
    for (int m = 0; m < kN; ++m){ float e = expf(prow[m] - mx); prow[m] = e; sum += e; }
    float inv = 1.f / sum;
    float o[32];
    #pragma unroll
    for (int d = 0; d < 32; ++d) o[d] = 0.f;
    for (int m = 0; m < kN; ++m){
      float p = prow[m];
      #pragma unroll
      for (int d = 0; d < 32; ++d) o[d] += p * vs[m*32 + d];
    }
    bf* op = out + ((size_t)lw*kN + t)*kC + h*32;
    #pragma unroll
    for (int d = 0; d < 32; ++d) op[d] = f2b(o[d] * inv);
  }
}

extern "C" void kernel_launch(void* const* d_in, const int* in_sizes, int n_in,
                              void* d_out, int out_size, void* d_ws, size_t ws_size,
                              hipStream_t stream){
  (void)in_sizes; (void)n_in; (void)out_size; (void)ws_size;
  const float* x     = (const float*)d_in[0];
  const float* n1g   = (const float*)d_in[1];
  const float* n1b   = (const float*)d_in[2];
  const float* qkvw  = (const float*)d_in[3];
  const float* qkvb  = (const float*)d_in[4];
  const float* relb  = (const float*)d_in[5];
  const float* projw = (const float*)d_in[6];
  const float* projb = (const float*)d_in[7];
  const float* n2g   = (const float*)d_in[8];
  const float* n2b   = (const float*)d_in[9];
  const float* fc1w  = (const float*)d_in[10];
  const float* fc1b  = (const float*)d_in[11];
  const float* fc2w  = (const float*)d_in[12];
  const float* fc2b  = (const float*)d_in[13];
  float* out = (float*)d_out;

  char* w = (char*)d_ws;
  const size_t WINB  = 19267584;   // 25088*384*2
  const size_t BIGB  = 77070336;   // 25088*1536*2 (qkv planes / mlp hidden)
  bf* winbuf = (bf*)w;             // ln output; also reused as attention output
  bf* big    = (bf*)(w + WINB);
  bf* wts    = (bf*)(w + WINB + BIGB);
  bf* qkvwt  = wts;                 // [1152][384]
  bf* projwt = qkvwt + 442368;      // [384][384]
  bf* fc1wt  = projwt + 147456;     // [1536][384]
  bf* fc2wt  = fc1wt + 589824;      // [384][1536]
  bf* qb = big; bf* kb = big + kPlane; bf* vb = big + 2*(size_t)kPlane;

  tr_k<<<dim3((442368+255)/256), 256, 0, stream>>>(qkvw,  qkvwt, 384, 1152);
  tr_k<<<dim3((147456+255)/256), 256, 0, stream>>>(projw, projwt, 384, 384);
  tr_k<<<dim3((589824+255)/256), 256, 0, stream>>>(fc1w,  fc1wt, 384, 1536);
  tr_k<<<dim3((589824+255)/256), 256, 0, stream>>>(fc2w,  fc2wt, 1536, 384);

  // attention path, 4 window chunks; proj epilogue writes x1 = x + attn (f32) into d_out
  for (int c = 0; c < 4; ++c){
    int winbase = c * kChunkWins;
    ln_k<1><<<kChunkRows/4, 256, 0, stream>>>(x, n1g, n1b, winbuf, winbase);
    gemm_k<0><<<196*9, 256, 0, stream>>>(winbuf, qkvwt, qkvb, 384, 9,
                                         qb, kb, vb, nullptr, nullptr, 0);
    attn_k<<<kChunkWins*kHeads, 64, 0, stream>>>(qb, kb, vb, relb, winbuf);
    gemm_k<1><<<196*3, 256, 0, stream>>>(winbuf, projwt, projb, 384, 3,
                                         nullptr, nullptr, nullptr, out, x, winbase);
  }
  // MLP path on x1 rows (f32, in d_out), 4 row chunks; fc2 adds residual in place
  for (int c = 0; c < 4; ++c){
    float* xr = out + (size_t)c * kChunkRows * kC;
    ln_k<0><<<kChunkRows/4, 256, 0, stream>>>(xr, n2g, n2b, winbuf, 0);
    gemm_k<2><<<196*12, 256, 0, stream>>>(winbuf, fc1wt, fc1b, 384, 12,
                                          big, nullptr, nullptr, nullptr, nullptr, 0);
    gemm_k<3><<<196*3, 256, 0, stream>>>(big, fc2wt, fc2b, 1536, 3,
                                         nullptr, nullptr, nullptr, xr, xr, 0);
  }
}

// Round 5
// 1228.226 us; speedup vs baseline: 1.3093x; 1.2559x over previous
//
#include <hip/hip_runtime.h>
#include <hip/hip_bf16.h>
#include <math.h>

using bf = __hip_bfloat16;
typedef unsigned short u16;
typedef __attribute__((ext_vector_type(8))) unsigned short us8;
typedef __attribute__((ext_vector_type(8))) __bf16 bf16x8;
typedef __attribute__((ext_vector_type(4))) float f32x4;

static constexpr int kC    = 384;
static constexpr int kHid  = 1536;
static constexpr int kHeads= 12;
static constexpr int kN    = 49;
static constexpr float kScale = 0.17677669529663687f;  // 32^-0.5
static constexpr int kChunkWins = 512;
static constexpr int kChunkRows = kChunkWins * kN;      // 25088
static constexpr int kPlane = kChunkWins * kHeads * kN * 32;

__device__ __forceinline__ float b2f(bf v){ return __bfloat162float(v); }
__device__ __forceinline__ bf    f2b(float v){ return __float2bfloat16(v); }

__device__ __forceinline__ void gload16(const void* g, void* l){
  __builtin_amdgcn_global_load_lds(
      (const __attribute__((address_space(1))) void*)g,
      (__attribute__((address_space(3))) void*)l, 16, 0, 0);
}

// ---------------- weight transpose: out[n*K+k] = bf16(in[k*N+n]) ----------
__global__ void tr_k(const float* __restrict__ in, bf* __restrict__ out, int K, int N){
  int i = blockIdx.x*256 + threadIdx.x;
  if (i < K*N){ int k = i / N, n = i - k*N; out[(size_t)n*K + k] = f2b(in[i]); }
}

// ---- LayerNorm. GATHER=1: fused shift + window partition ----
template<int GATHER>
__global__ __launch_bounds__(256) void ln_k(const float* __restrict__ x, const float* __restrict__ g,
                                            const float* __restrict__ be, bf* __restrict__ out,
                                            int winbase){
  int wv = threadIdx.x >> 6, lane = threadIdx.x & 63;
  int lr = blockIdx.x*4 + wv;
  const float* src;
  if constexpr (GATHER){
    int win = lr / kN, n = lr - win*kN;
    int gw = winbase + win;
    int b = gw >> 6, rem = gw & 63, wh = rem >> 3, ww = rem & 7;
    int ih = n / 7, iw = n - ih*7;
    int h0 = (wh*7 + ih + 3) % 56;
    int w0 = (ww*7 + iw + 3) % 56;
    src = x + ((size_t)b*3136 + h0*56 + w0) * kC;
  } else {
    src = x + (size_t)lr * kC;
  }
  float vals[6]; float s = 0.f, sq = 0.f;
  #pragma unroll
  for (int j = 0; j < 6; ++j){ float f = src[j*64 + lane]; vals[j] = f; s += f; sq += f*f; }
  #pragma unroll
  for (int o = 32; o > 0; o >>= 1){ s += __shfl_down(s, o); sq += __shfl_down(sq, o); }
  s = __shfl(s, 0); sq = __shfl(sq, 0);
  float mean = s * (1.f/384.f);
  float var  = sq * (1.f/384.f) - mean*mean;
  float rstd = rsqrtf(var + 1e-5f);
  bf* dst = out + (size_t)lr * kC;
  #pragma unroll
  for (int j = 0; j < 6; ++j){
    int c = j*64 + lane;
    dst[c] = f2b((vals[j]-mean)*rstd*g[c] + be[c]);
  }
}

// ---- 3-deep pipelined 128x128 bf16 MFMA GEMM, BK=32, counted vmcnt ----
// LDS XOR-swizzled (unit = 16B): store unit j_data at j_data^((row>>1)&3),
// achieved by pre-swizzling the GLOBAL source col (linear gload_lds dest).
template<int EPI>
__global__ __launch_bounds__(256) void gemm_k(const bf* __restrict__ A, const bf* __restrict__ Wt,
                                              const float* __restrict__ bias, int K, int nbn,
                                              bf* o0, bf* o1, bf* o2,
                                              float* fo, const float* res, int aux){
  __shared__ u16 sA[3][4096];
  __shared__ u16 sB[3][4096];
  int nwg = gridDim.x, id = blockIdx.x;
  int q = nwg >> 3, r = nwg & 7, xcd = id & 7, off = id >> 3;
  int swz = (xcd < r ? xcd*(q+1) : r*(q+1) + (xcd-r)*q) + off;
  int bm = (swz / nbn) << 7, bn = (swz % nbn) << 7;

  int t = threadIdx.x, lane = t & 63, wv = t >> 6;
  // stage: wave wv owns rows [wv*32, wv*32+32); source col unit pre-swizzled
  int scol = ((lane & 3) ^ ((lane >> 3) & 3)) * 8;
  const u16* Ag = (const u16*)A  + (size_t)(bm + wv*32 + (lane >> 2))*K + scol;
  const u16* Bg = (const u16*)Wt + (size_t)(bn + wv*32 + (lane >> 2))*K + scol;
  size_t rstep = (size_t)16 * K;
  int l0 = wv*32*32;                      // u16 index of wave's LDS region

  int wr = wv >> 1, wc = wv & 1, lr = lane & 15, lk = lane >> 4;
  int runit = lk ^ ((lr >> 1) & 3);       // swizzled read unit
  int ro = (wr*64 + lr)*32 + runit*8;
  int co = (wc*64 + lr)*32 + runit*8;
  f32x4 acc[4][4];
  #pragma unroll
  for (int i = 0; i < 4; ++i)
    #pragma unroll
    for (int j = 0; j < 4; ++j) acc[i][j] = (f32x4){0.f,0.f,0.f,0.f};

  int nst = K >> 5;                        // 12 or 48 (multiple of 3)
  #define STG(tt, b) { \
    const u16* ag_ = Ag + (tt)*32; const u16* bg_ = Bg + (tt)*32; \
    gload16(ag_,         &sA[b][l0]);       gload16(ag_ + rstep, &sA[b][l0 + 512]); \
    gload16(bg_,         &sB[b][l0]);       gload16(bg_ + rstep, &sB[b][l0 + 512]); }
  #define STEP(b, tt) { \
    if ((tt) + 2 < nst)      asm volatile("s_waitcnt vmcnt(8)" ::: "memory"); \
    else if ((tt) + 1 < nst) asm volatile("s_waitcnt vmcnt(4)" ::: "memory"); \
    else                     asm volatile("s_waitcnt vmcnt(0)" ::: "memory"); \
    __builtin_amdgcn_s_barrier(); \
    bf16x8 af[4], bfr[4]; \
    _Pragma("unroll") \
    for (int mi = 0; mi < 4; ++mi) af[mi]  = __builtin_bit_cast(bf16x8, *(const us8*)&sA[b][ro + mi*512]); \
    _Pragma("unroll") \
    for (int ni = 0; ni < 4; ++ni) bfr[ni] = __builtin_bit_cast(bf16x8, *(const us8*)&sB[b][co + ni*512]); \
    _Pragma("unroll") \
    for (int mi = 0; mi < 4; ++mi) \
      _Pragma("unroll") \
      for (int ni = 0; ni < 4; ++ni) \
        acc[mi][ni] = __builtin_amdgcn_mfma_f32_16x16x32_bf16(af[mi], bfr[ni], acc[mi][ni], 0, 0, 0); \
    asm volatile("s_waitcnt lgkmcnt(0)" ::: "memory"); \
    __builtin_amdgcn_s_barrier(); \
    if ((tt) + 3 < nst) STG((tt) + 3, b); }

  STG(0, 0); STG(1, 1); STG(2, 2);
  for (int tt = 0; tt < nst; tt += 3){
    STEP(0, tt); STEP(1, tt + 1); STEP(2, tt + 2);
  }
  #undef STEP
  #undef STG

  // ---------------- epilogue (ni innermost for 128B-adjacent stores) ------
  float bs[4];
  #pragma unroll
  for (int ni = 0; ni < 4; ++ni) bs[ni] = bias[bn + wc*64 + ni*16 + lr];
  #pragma unroll
  for (int mi = 0; mi < 4; ++mi){
    #pragma unroll
    for (int r2 = 0; r2 < 4; ++r2){
      int row = bm + wr*64 + mi*16 + lk*4 + r2;
      if constexpr (EPI == 0){
        int win = row / kN, n = row - win*kN;
        size_t rb = (size_t)(win*kHeads)*(kN*32) + n*32;
        #pragma unroll
        for (int ni = 0; ni < 4; ++ni){
          int col = bn + wc*64 + ni*16 + lr;
          float v = acc[mi][ni][r2] + bs[ni];
          int which = col / kC; int cc = col - which*kC; int hd = cc >> 5, d = cc & 31;
          bf* dst = which == 0 ? o0 : (which == 1 ? o1 : o2);
          if (which == 0) v *= kScale;
          dst[rb + (size_t)hd*(kN*32) + d] = f2b(v);
        }
      } else if constexpr (EPI == 1){
        int win = row / kN, n = row - win*kN;
        int gw = aux + win;
        int b = gw >> 6, rem = gw & 63, wh = rem >> 3, ww = rem & 7;
        int ih = n / 7, iw = n - ih*7;
        int h0 = (wh*7 + ih + 3) % 56;
        int w0 = (ww*7 + iw + 3) % 56;
        size_t base = ((size_t)b*3136 + h0*56 + w0)*kC;
        #pragma unroll
        for (int ni = 0; ni < 4; ++ni){
          int col = bn + wc*64 + ni*16 + lr;
          fo[base + col] = acc[mi][ni][r2] + bs[ni] + res[base + col];
        }
      } else if constexpr (EPI == 2){
        size_t base = (size_t)row*kHid;
        #pragma unroll
        for (int ni = 0; ni < 4; ++ni){
          int col = bn + wc*64 + ni*16 + lr;
          float v = acc[mi][ni][r2] + bs[ni];
          v = 0.5f * v * (1.f + erff(v * 0.70710678118654752f));
          o0[base + col] = f2b(v);
        }
      } else {
        size_t base = (size_t)row*kC;
        #pragma unroll
        for (int ni = 0; ni < 4; ++ni){
          int col = bn + wc*64 + ni*16 + lr;
          fo[base + col] = acc[mi][ni][r2] + bs[ni] + res[base + col];
        }
      }
    }
  }
}

// --------------------------- window attention -----------------------------
__global__ __launch_bounds__(64) void attn_k(const bf* __restrict__ q, const bf* __restrict__ kkk,
                                             const bf* __restrict__ vvv, const float* __restrict__ relb,
                                             bf* __restrict__ out){
  __shared__ float ks[kN*32], vs[kN*32], ps[kN*52];
  int bid = blockIdx.x, lw = bid / kHeads, h = bid - lw*kHeads;
  const bf* qp = q   + (size_t)bid * (kN*32);
  const bf* kp = kkk + (size_t)bid * (kN*32);
  const bf* vp = vvv + (size_t)bid * (kN*32);
  int t = threadIdx.x;
  for (int i = t; i < kN*32; i += 64){ ks[i] = b2f(kp[i]); vs[i] = b2f(vp[i]); }
  __syncthreads();
  if (t < kN){
    float qr[32];
    #pragma unroll
    for (int d = 0; d < 32; ++d) qr[d] = b2f(qp[t*32 + d]);
    int ih = t / 7, iw = t - ih*7;
    float* prow = &ps[t*52];
    for (int m = 0; m < kN; ++m){
      float a = 0.f;
      #pragma unroll
      for (int d = 0; d < 32; ++d) a += qr[d] * ks[m*32 + d];
      int kh = m / 7, kw = m - kh*7;
      a += relb[((ih - kh + 6)*13 + (iw - kw + 6))*kHeads + h];
      prow[m] = a;
    }
    float mx = -1e30f;
    for (int m = 0; m < kN; ++m) mx = fmaxf(mx, prow[m]);
    float sum = 0.f;
    for (int m = 0; m < kN; ++m){ float e = expf(prow[m] - mx); prow[m] = e; sum += e; }
    float inv = 1.f / sum;
    float o[32];
    #pragma unroll
    for (int d = 0; d < 32; ++d) o[d] = 0.f;
    for (int m = 0; m < kN; ++m){
      float p = prow[m];
      #pragma unroll
      for (int d = 0; d < 32; ++d) o[d] += p * vs[m*32 + d];
    }
    bf* op = out + ((size_t)lw*kN + t)*kC + h*32;
    #pragma unroll
    for (int d = 0; d < 32; ++d) op[d] = f2b(o[d] * inv);
  }
}

extern "C" void kernel_launch(void* const* d_in, const int* in_sizes, int n_in,
                              void* d_out, int out_size, void* d_ws, size_t ws_size,
                              hipStream_t stream){
  (void)in_sizes; (void)n_in; (void)out_size; (void)ws_size;
  const float* x     = (const float*)d_in[0];
  const float* n1g   = (const float*)d_in[1];
  const float* n1b   = (const float*)d_in[2];
  const float* qkvw  = (const float*)d_in[3];
  const float* qkvb  = (const float*)d_in[4];
  const float* relb  = (const float*)d_in[5];
  const float* projw = (const float*)d_in[6];
  const float* projb = (const float*)d_in[7];
  const float* n2g   = (const float*)d_in[8];
  const float* n2b   = (const float*)d_in[9];
  const float* fc1w  = (const float*)d_in[10];
  const float* fc1b  = (const float*)d_in[11];
  const float* fc2w  = (const float*)d_in[12];
  const float* fc2b  = (const float*)d_in[13];
  float* out = (float*)d_out;

  char* w = (char*)d_ws;
  const size_t WINB  = 19267584;   // 25088*384*2
  const size_t BIGB  = 77070336;   // 25088*1536*2
  bf* winbuf = (bf*)w;
  bf* big    = (bf*)(w + WINB);
  bf* wts    = (bf*)(w + WINB + BIGB);
  bf* qkvwt  = wts;
  bf* projwt = qkvwt + 442368;
  bf* fc1wt  = projwt + 147456;
  bf* fc2wt  = fc1wt + 589824;
  bf* qb = big; bf* kb = big + kPlane; bf* vb = big + 2*(size_t)kPlane;

  tr_k<<<dim3((442368+255)/256), 256, 0, stream>>>(qkvw,  qkvwt, 384, 1152);
  tr_k<<<dim3((147456+255)/256), 256, 0, stream>>>(projw, projwt, 384, 384);
  tr_k<<<dim3((589824+255)/256), 256, 0, stream>>>(fc1w,  fc1wt, 384, 1536);
  tr_k<<<dim3((589824+255)/256), 256, 0, stream>>>(fc2w,  fc2wt, 1536, 384);

  for (int c = 0; c < 4; ++c){
    int winbase = c * kChunkWins;
    ln_k<1><<<kChunkRows/4, 256, 0, stream>>>(x, n1g, n1b, winbuf, winbase);
    gemm_k<0><<<196*9, 256, 0, stream>>>(winbuf, qkvwt, qkvb, 384, 9,
                                         qb, kb, vb, nullptr, nullptr, 0);
    attn_k<<<kChunkWins*kHeads, 64, 0, stream>>>(qb, kb, vb, relb, winbuf);
    gemm_k<1><<<196*3, 256, 0, stream>>>(winbuf, projwt, projb, 384, 3,
                                         nullptr, nullptr, nullptr, out, x, winbase);
  }
  for (int c = 0; c < 4; ++c){
    float* xr = out + (size_t)c * kChunkRows * kC;
    ln_k<0><<<kChunkRows/4, 256, 0, stream>>>(xr, n2g, n2b, winbuf, 0);
    gemm_k<2><<<196*12, 256, 0, stream>>>(winbuf, fc1wt, fc1b, 384, 12,
                                          big, nullptr, nullptr, nullptr, nullptr, 0);
    gemm_k<3><<<196*3, 256, 0, stream>>>(big, fc2wt, fc2b, 1536, 3,
                                         nullptr, nullptr, nullptr, xr, xr, 0);
  }
}

// Round 6
// 1214.842 us; speedup vs baseline: 1.3237x; 1.0110x over previous
//
#include <hip/hip_runtime.h>
#include <hip/hip_bf16.h>
#include <math.h>

using bf = __hip_bfloat16;
typedef unsigned short u16;
typedef __attribute__((ext_vector_type(8))) unsigned short us8;
typedef __attribute__((ext_vector_type(8))) __bf16 bf16x8;
typedef __attribute__((ext_vector_type(4))) float f32x4;

static constexpr int kC    = 384;
static constexpr int kHid  = 1536;
static constexpr int kHeads= 12;
static constexpr int kN    = 49;
static constexpr float kScale = 0.17677669529663687f;  // 32^-0.5
static constexpr int kChunkWins = 512;
static constexpr int kChunkRows = kChunkWins * kN;      // 25088
static constexpr int kPlane = kChunkWins * kHeads * kN * 32;

__device__ __forceinline__ float b2f(bf v){ return __bfloat162float(v); }
__device__ __forceinline__ bf    f2b(float v){ return __float2bfloat16(v); }

__device__ __forceinline__ void gload16(const void* g, void* l){
  __builtin_amdgcn_global_load_lds(
      (const __attribute__((address_space(1))) void*)g,
      (__attribute__((address_space(3))) void*)l, 16, 0, 0);
}

// ---------------- weight transpose: out[n*K+k] = bf16(in[k*N+n]) ----------
__global__ void tr_k(const float* __restrict__ in, bf* __restrict__ out, int K, int N){
  int i = blockIdx.x*256 + threadIdx.x;
  if (i < K*N){ int k = i / N, n = i - k*N; out[(size_t)n*K + k] = f2b(in[i]); }
}

// ---- LayerNorm. GATHER=1: fused shift + window partition ----
template<int GATHER>
__global__ __launch_bounds__(256) void ln_k(const float* __restrict__ x, const float* __restrict__ g,
                                            const float* __restrict__ be, bf* __restrict__ out,
                                            int winbase){
  int wv = threadIdx.x >> 6, lane = threadIdx.x & 63;
  int lr = blockIdx.x*4 + wv;
  const float* src;
  if constexpr (GATHER){
    int win = lr / kN, n = lr - win*kN;
    int gw = winbase + win;
    int b = gw >> 6, rem = gw & 63, wh = rem >> 3, ww = rem & 7;
    int ih = n / 7, iw = n - ih*7;
    int h0 = (wh*7 + ih + 3) % 56;
    int w0 = (ww*7 + iw + 3) % 56;
    src = x + ((size_t)b*3136 + h0*56 + w0) * kC;
  } else {
    src = x + (size_t)lr * kC;
  }
  float vals[6]; float s = 0.f, sq = 0.f;
  #pragma unroll
  for (int j = 0; j < 6; ++j){ float f = src[j*64 + lane]; vals[j] = f; s += f; sq += f*f; }
  #pragma unroll
  for (int o = 32; o > 0; o >>= 1){ s += __shfl_down(s, o); sq += __shfl_down(sq, o); }
  s = __shfl(s, 0); sq = __shfl(sq, 0);
  float mean = s * (1.f/384.f);
  float var  = sq * (1.f/384.f) - mean*mean;
  float rstd = rsqrtf(var + 1e-5f);
  bf* dst = out + (size_t)lr * kC;
  #pragma unroll
  for (int j = 0; j < 6; ++j){
    int c = j*64 + lane;
    dst[c] = f2b((vals[j]-mean)*rstd*g[c] + be[c]);
  }
}

// ---- 3-deep pipelined 128x128 bf16 MFMA GEMM, BK=32, counted vmcnt ----
template<int EPI>
__global__ __launch_bounds__(256) void gemm_k(const bf* __restrict__ A, const bf* __restrict__ Wt,
                                              const float* __restrict__ bias, int K, int nbn,
                                              bf* o0, bf* o1, bf* o2,
                                              float* fo, const float* res, int aux){
  __shared__ u16 sA[3][4096];
  __shared__ u16 sB[3][4096];
  int nwg = gridDim.x, id = blockIdx.x;
  int q = nwg >> 3, r = nwg & 7, xcd = id & 7, off = id >> 3;
  int swz = (xcd < r ? xcd*(q+1) : r*(q+1) + (xcd-r)*q) + off;
  int bm = (swz / nbn) << 7, bn = (swz % nbn) << 7;

  int t = threadIdx.x, lane = t & 63, wv = t >> 6;
  int scol = ((lane & 3) ^ ((lane >> 3) & 3)) * 8;
  const u16* Ag = (const u16*)A  + (size_t)(bm + wv*32 + (lane >> 2))*K + scol;
  const u16* Bg = (const u16*)Wt + (size_t)(bn + wv*32 + (lane >> 2))*K + scol;
  size_t rstep = (size_t)16 * K;
  int l0 = wv*32*32;

  int wr = wv >> 1, wc = wv & 1, lr = lane & 15, lk = lane >> 4;
  int runit = lk ^ ((lr >> 1) & 3);
  int ro = (wr*64 + lr)*32 + runit*8;
  int co = (wc*64 + lr)*32 + runit*8;
  f32x4 acc[4][4];
  #pragma unroll
  for (int i = 0; i < 4; ++i)
    #pragma unroll
    for (int j = 0; j < 4; ++j) acc[i][j] = (f32x4){0.f,0.f,0.f,0.f};

  int nst = K >> 5;
  #define STG(tt, b) { \
    const u16* ag_ = Ag + (tt)*32; const u16* bg_ = Bg + (tt)*32; \
    gload16(ag_,         &sA[b][l0]);       gload16(ag_ + rstep, &sA[b][l0 + 512]); \
    gload16(bg_,         &sB[b][l0]);       gload16(bg_ + rstep, &sB[b][l0 + 512]); }
  #define STEP(b, tt) { \
    if ((tt) + 2 < nst)      asm volatile("s_waitcnt vmcnt(8)" ::: "memory"); \
    else if ((tt) + 1 < nst) asm volatile("s_waitcnt vmcnt(4)" ::: "memory"); \
    else                     asm volatile("s_waitcnt vmcnt(0)" ::: "memory"); \
    __builtin_amdgcn_s_barrier(); \
    bf16x8 af[4], bfr[4]; \
    _Pragma("unroll") \
    for (int mi = 0; mi < 4; ++mi) af[mi]  = __builtin_bit_cast(bf16x8, *(const us8*)&sA[b][ro + mi*512]); \
    _Pragma("unroll") \
    for (int ni = 0; ni < 4; ++ni) bfr[ni] = __builtin_bit_cast(bf16x8, *(const us8*)&sB[b][co + ni*512]); \
    _Pragma("unroll") \
    for (int mi = 0; mi < 4; ++mi) \
      _Pragma("unroll") \
      for (int ni = 0; ni < 4; ++ni) \
        acc[mi][ni] = __builtin_amdgcn_mfma_f32_16x16x32_bf16(af[mi], bfr[ni], acc[mi][ni], 0, 0, 0); \
    asm volatile("s_waitcnt lgkmcnt(0)" ::: "memory"); \
    __builtin_amdgcn_s_barrier(); \
    if ((tt) + 3 < nst) STG((tt) + 3, b); }

  STG(0, 0); STG(1, 1); STG(2, 2);
  for (int tt = 0; tt < nst; tt += 3){
    STEP(0, tt); STEP(1, tt + 1); STEP(2, tt + 2);
  }
  #undef STEP
  #undef STG

  float bs[4];
  #pragma unroll
  for (int ni = 0; ni < 4; ++ni) bs[ni] = bias[bn + wc*64 + ni*16 + lr];
  #pragma unroll
  for (int mi = 0; mi < 4; ++mi){
    #pragma unroll
    for (int r2 = 0; r2 < 4; ++r2){
      int row = bm + wr*64 + mi*16 + lk*4 + r2;
      if constexpr (EPI == 0){
        int win = row / kN, n = row - win*kN;
        size_t rb = (size_t)(win*kHeads)*(kN*32) + n*32;
        #pragma unroll
        for (int ni = 0; ni < 4; ++ni){
          int col = bn + wc*64 + ni*16 + lr;
          float v = acc[mi][ni][r2] + bs[ni];
          int which = col / kC; int cc = col - which*kC; int hd = cc >> 5, d = cc & 31;
          bf* dst = which == 0 ? o0 : (which == 1 ? o1 : o2);
          if (which == 0) v *= kScale;
          dst[rb + (size_t)hd*(kN*32) + d] = f2b(v);
        }
      } else if constexpr (EPI == 1){
        int win = row / kN, n = row - win*kN;
        int gw = aux + win;
        int b = gw >> 6, rem = gw & 63, wh = rem >> 3, ww = rem & 7;
        int ih = n / 7, iw = n - ih*7;
        int h0 = (wh*7 + ih + 3) % 56;
        int w0 = (ww*7 + iw + 3) % 56;
        size_t base = ((size_t)b*3136 + h0*56 + w0)*kC;
        #pragma unroll
        for (int ni = 0; ni < 4; ++ni){
          int col = bn + wc*64 + ni*16 + lr;
          fo[base + col] = acc[mi][ni][r2] + bs[ni] + res[base + col];
        }
      } else if constexpr (EPI == 2){
        size_t base = (size_t)row*kHid;
        #pragma unroll
        for (int ni = 0; ni < 4; ++ni){
          int col = bn + wc*64 + ni*16 + lr;
          float v = acc[mi][ni][r2] + bs[ni];
          v = 0.5f * v * (1.f + erff(v * 0.70710678118654752f));
          o0[base + col] = f2b(v);
        }
      } else {
        size_t base = (size_t)row*kC;
        #pragma unroll
        for (int ni = 0; ni < 4; ++ni){
          int col = bn + wc*64 + ni*16 + lr;
          fo[base + col] = acc[mi][ni][r2] + bs[ni] + res[base + col];
        }
      }
    }
  }
}

// --------------------------- window attention v2 --------------------------
// 4 waves/block, one (win,head) per wave. Scores in registers (full unroll),
// K/V f32 in LDS (broadcast reads, conflict-free), rel-bias staged in LDS.
__global__ __launch_bounds__(256) void attn_k(const bf* __restrict__ q, const bf* __restrict__ kkk,
                                              const bf* __restrict__ vvv, const float* __restrict__ relb,
                                              bf* __restrict__ out){
  __shared__ float rbs[169*kHeads];          // 8112 B
  __shared__ float kv[4][2][kN*32];          // 50176 B
  int t = threadIdx.x, wv = t >> 6, lane = t & 63;
  for (int i = t; i < 169*kHeads; i += 256) rbs[i] = relb[i];

  int bid = blockIdx.x*4 + wv;               // win*12 + h
  int lw = bid / kHeads, h = bid - lw*kHeads;
  const bf* kp = kkk + (size_t)bid * (kN*32);
  const bf* vp = vvv + (size_t)bid * (kN*32);
  // vectorized stage: 196 us8-units per plane
  for (int u = lane; u < 196; u += 64){
    us8 kvk = *((const us8*)kp + u);
    us8 kvv = *((const us8*)vp + u);
    #pragma unroll
    for (int j = 0; j < 8; ++j){
      kv[wv][0][u*8 + j] = b2f(__builtin_bit_cast(bf, (u16)kvk[j]));
      kv[wv][1][u*8 + j] = b2f(__builtin_bit_cast(bf, (u16)kvv[j]));
    }
  }
  __syncthreads();

  int row = lane < kN ? lane : kN - 1;
  const bf* qp = q + (size_t)bid * (kN*32) + row*32;
  float qr[32];
  #pragma unroll
  for (int d = 0; d < 32; ++d) qr[d] = b2f(qp[d]);

  const float* ks = kv[wv][0];
  const float* vs = kv[wv][1];
  int ih = row / 7, iw = row - (row/7)*7;
  float p[kN];
  float mx = -1e30f;
  #pragma unroll
  for (int m = 0; m < kN; ++m){
    float a0 = 0.f, a1 = 0.f, a2 = 0.f, a3 = 0.f;
    #pragma unroll
    for (int d = 0; d < 32; d += 4){
      a0 += qr[d]   * ks[m*32 + d];
      a1 += qr[d+1] * ks[m*32 + d+1];
      a2 += qr[d+2] * ks[m*32 + d+2];
      a3 += qr[d+3] * ks[m*32 + d+3];
    }
    int kh = m / 7, kw = m - kh*7;
    float a = (a0 + a1) + (a2 + a3) + rbs[((ih - kh + 6)*13 + (iw - kw + 6))*kHeads + h];
    p[m] = a;
    mx = fmaxf(mx, a);
  }
  float s0 = 0.f, s1 = 0.f, s2 = 0.f, s3 = 0.f;
  #pragma unroll
  for (int m = 0; m < kN; m += 4){
    p[m] = __expf(p[m] - mx);               s0 += p[m];
    if (m+1 < kN){ p[m+1] = __expf(p[m+1] - mx); s1 += p[m+1]; }
    if (m+2 < kN){ p[m+2] = __expf(p[m+2] - mx); s2 += p[m+2]; }
    if (m+3 < kN){ p[m+3] = __expf(p[m+3] - mx); s3 += p[m+3]; }
  }
  float inv = 1.f / ((s0 + s1) + (s2 + s3));

  float o[32];
  #pragma unroll
  for (int d = 0; d < 32; ++d) o[d] = 0.f;
  #pragma unroll
  for (int m = 0; m < kN; ++m){
    float pm = p[m];
    #pragma unroll
    for (int d = 0; d < 32; ++d) o[d] += pm * vs[m*32 + d];
  }

  if (lane < kN){
    bf* op = out + ((size_t)lw*kN + lane)*kC + h*32;
    #pragma unroll
    for (int b8 = 0; b8 < 4; ++b8){
      us8 wdat;
      #pragma unroll
      for (int j = 0; j < 8; ++j)
        wdat[j] = __builtin_bit_cast(u16, f2b(o[b8*8 + j] * inv));
      *(us8*)(op + b8*8) = wdat;
    }
  }
}

extern "C" void kernel_launch(void* const* d_in, const int* in_sizes, int n_in,
                              void* d_out, int out_size, void* d_ws, size_t ws_size,
                              hipStream_t stream){
  (void)in_sizes; (void)n_in; (void)out_size; (void)ws_size;
  const float* x     = (const float*)d_in[0];
  const float* n1g   = (const float*)d_in[1];
  const float* n1b   = (const float*)d_in[2];
  const float* qkvw  = (const float*)d_in[3];
  const float* qkvb  = (const float*)d_in[4];
  const float* relb  = (const float*)d_in[5];
  const float* projw = (const float*)d_in[6];
  const float* projb = (const float*)d_in[7];
  const float* n2g   = (const float*)d_in[8];
  const float* n2b   = (const float*)d_in[9];
  const float* fc1w  = (const float*)d_in[10];
  const float* fc1b  = (const float*)d_in[11];
  const float* fc2w  = (const float*)d_in[12];
  const float* fc2b  = (const float*)d_in[13];
  float* out = (float*)d_out;

  char* w = (char*)d_ws;
  const size_t WINB  = 19267584;   // 25088*384*2
  const size_t BIGB  = 77070336;   // 25088*1536*2
  bf* winbuf = (bf*)w;
  bf* big    = (bf*)(w + WINB);
  bf* wts    = (bf*)(w + WINB + BIGB);
  bf* qkvwt  = wts;
  bf* projwt = qkvwt + 442368;
  bf* fc1wt  = projwt + 147456;
  bf* fc2wt  = fc1wt + 589824;
  bf* qb = big; bf* kb = big + kPlane; bf* vb = big + 2*(size_t)kPlane;

  tr_k<<<dim3((442368+255)/256), 256, 0, stream>>>(qkvw,  qkvwt, 384, 1152);
  tr_k<<<dim3((147456+255)/256), 256, 0, stream>>>(projw, projwt, 384, 384);
  tr_k<<<dim3((589824+255)/256), 256, 0, stream>>>(fc1w,  fc1wt, 384, 1536);
  tr_k<<<dim3((589824+255)/256), 256, 0, stream>>>(fc2w,  fc2wt, 1536, 384);

  for (int c = 0; c < 4; ++c){
    int winbase = c * kChunkWins;
    ln_k<1><<<kChunkRows/4, 256, 0, stream>>>(x, n1g, n1b, winbuf, winbase);
    gemm_k<0><<<196*9, 256, 0, stream>>>(winbuf, qkvwt, qkvb, 384, 9,
                                         qb, kb, vb, nullptr, nullptr, 0);
    attn_k<<<kChunkWins*kHeads/4, 256, 0, stream>>>(qb, kb, vb, relb, winbuf);
    gemm_k<1><<<196*3, 256, 0, stream>>>(winbuf, projwt, projb, 384, 3,
                                         nullptr, nullptr, nullptr, out, x, winbase);
  }
  for (int c = 0; c < 4; ++c){
    float* xr = out + (size_t)c * kChunkRows * kC;
    ln_k<0><<<kChunkRows/4, 256, 0, stream>>>(xr, n2g, n2b, winbuf, 0);
    gemm_k<2><<<196*12, 256, 0, stream>>>(winbuf, fc1wt, fc1b, 384, 12,
                                          big, nullptr, nullptr, nullptr, nullptr, 0);
    gemm_k<3><<<196*3, 256, 0, stream>>>(big, fc2wt, fc2b, 1536, 3,
                                         nullptr, nullptr, nullptr, xr, xr, 0);
  }
}

// Round 7
// 1210.507 us; speedup vs baseline: 1.3284x; 1.0036x over previous
//
#include <hip/hip_runtime.h>
#include <hip/hip_bf16.h>
#include <math.h>

using bf = __hip_bfloat16;
typedef unsigned short u16;
typedef __attribute__((ext_vector_type(8))) unsigned short us8;
typedef __attribute__((ext_vector_type(8))) __bf16 bf16x8;
typedef __attribute__((ext_vector_type(4))) float f32x4;

static constexpr int kC    = 384;
static constexpr int kHid  = 1536;
static constexpr int kHeads= 12;
static constexpr int kN    = 49;
static constexpr float kScale = 0.17677669529663687f;  // 32^-0.5
static constexpr int kChunkWins = 512;
static constexpr int kChunkRows = kChunkWins * kN;      // 25088
static constexpr int kPlane = kChunkWins * kHeads * 2048; // 12,582,912 elems

__device__ __forceinline__ float b2f(bf v){ return __bfloat162float(v); }
__device__ __forceinline__ bf    f2b(float v){ return __float2bfloat16(v); }

__device__ __forceinline__ void gload16(const void* g, void* l){
  __builtin_amdgcn_global_load_lds(
      (const __attribute__((address_space(1))) void*)g,
      (__attribute__((address_space(3))) void*)l, 16, 0, 0);
}

// ---------------- weight transpose: out[n*K+k] = bf16(in[k*N+n]) ----------
__global__ void tr_k(const float* __restrict__ in, bf* __restrict__ out, int K, int N){
  int i = blockIdx.x*256 + threadIdx.x;
  if (i < K*N){ int k = i / N, n = i - k*N; out[(size_t)n*K + k] = f2b(in[i]); }
}

// ---- LayerNorm. GATHER=1: fused shift + window partition ----
template<int GATHER>
__global__ __launch_bounds__(256) void ln_k(const float* __restrict__ x, const float* __restrict__ g,
                                            const float* __restrict__ be, bf* __restrict__ out,
                                            int winbase){
  int wv = threadIdx.x >> 6, lane = threadIdx.x & 63;
  int lr = blockIdx.x*4 + wv;
  const float* src;
  if constexpr (GATHER){
    int win = lr / kN, n = lr - win*kN;
    int gw = winbase + win;
    int b = gw >> 6, rem = gw & 63, wh = rem >> 3, ww = rem & 7;
    int ih = n / 7, iw = n - ih*7;
    int h0 = (wh*7 + ih + 3) % 56;
    int w0 = (ww*7 + iw + 3) % 56;
    src = x + ((size_t)b*3136 + h0*56 + w0) * kC;
  } else {
    src = x + (size_t)lr * kC;
  }
  float vals[6]; float s = 0.f, sq = 0.f;
  #pragma unroll
  for (int j = 0; j < 6; ++j){ float f = src[j*64 + lane]; vals[j] = f; s += f; sq += f*f; }
  #pragma unroll
  for (int o = 32; o > 0; o >>= 1){ s += __shfl_down(s, o); sq += __shfl_down(sq, o); }
  s = __shfl(s, 0); sq = __shfl(sq, 0);
  float mean = s * (1.f/384.f);
  float var  = sq * (1.f/384.f) - mean*mean;
  float rstd = rsqrtf(var + 1e-5f);
  bf* dst = out + (size_t)lr * kC;
  #pragma unroll
  for (int j = 0; j < 6; ++j){
    int c = j*64 + lane;
    dst[c] = f2b((vals[j]-mean)*rstd*g[c] + be[c]);
  }
}

// ---- 3-deep pipelined 128x128 bf16 MFMA GEMM, BK=32, counted vmcnt ----
template<int EPI>
__global__ __launch_bounds__(256) void gemm_k(const bf* __restrict__ A, const bf* __restrict__ Wt,
                                              const float* __restrict__ bias, int K, int nbn,
                                              bf* o0, bf* o1, bf* o2,
                                              float* fo, const float* res, int aux){
  __shared__ u16 sA[3][4096];
  __shared__ u16 sB[3][4096];
  int nwg = gridDim.x, id = blockIdx.x;
  int q = nwg >> 3, r = nwg & 7, xcd = id & 7, off = id >> 3;
  int swz = (xcd < r ? xcd*(q+1) : r*(q+1) + (xcd-r)*q) + off;
  int bm = (swz / nbn) << 7, bn = (swz % nbn) << 7;

  int t = threadIdx.x, lane = t & 63, wv = t >> 6;
  int scol = ((lane & 3) ^ ((lane >> 3) & 3)) * 8;
  const u16* Ag = (const u16*)A  + (size_t)(bm + wv*32 + (lane >> 2))*K + scol;
  const u16* Bg = (const u16*)Wt + (size_t)(bn + wv*32 + (lane >> 2))*K + scol;
  size_t rstep = (size_t)16 * K;
  int l0 = wv*32*32;

  int wr = wv >> 1, wc = wv & 1, lr = lane & 15, lk = lane >> 4;
  int runit = lk ^ ((lr >> 1) & 3);
  int ro = (wr*64 + lr)*32 + runit*8;
  int co = (wc*64 + lr)*32 + runit*8;
  f32x4 acc[4][4];
  #pragma unroll
  for (int i = 0; i < 4; ++i)
    #pragma unroll
    for (int j = 0; j < 4; ++j) acc[i][j] = (f32x4){0.f,0.f,0.f,0.f};

  int nst = K >> 5;
  #define STG(tt, b) { \
    const u16* ag_ = Ag + (tt)*32; const u16* bg_ = Bg + (tt)*32; \
    gload16(ag_,         &sA[b][l0]);       gload16(ag_ + rstep, &sA[b][l0 + 512]); \
    gload16(bg_,         &sB[b][l0]);       gload16(bg_ + rstep, &sB[b][l0 + 512]); }
  #define STEP(b, tt) { \
    if ((tt) + 2 < nst)      asm volatile("s_waitcnt vmcnt(8)" ::: "memory"); \
    else if ((tt) + 1 < nst) asm volatile("s_waitcnt vmcnt(4)" ::: "memory"); \
    else                     asm volatile("s_waitcnt vmcnt(0)" ::: "memory"); \
    __builtin_amdgcn_s_barrier(); \
    bf16x8 af[4], bfr[4]; \
    _Pragma("unroll") \
    for (int mi = 0; mi < 4; ++mi) af[mi]  = __builtin_bit_cast(bf16x8, *(const us8*)&sA[b][ro + mi*512]); \
    _Pragma("unroll") \
    for (int ni = 0; ni < 4; ++ni) bfr[ni] = __builtin_bit_cast(bf16x8, *(const us8*)&sB[b][co + ni*512]); \
    _Pragma("unroll") \
    for (int mi = 0; mi < 4; ++mi) \
      _Pragma("unroll") \
      for (int ni = 0; ni < 4; ++ni) \
        acc[mi][ni] = __builtin_amdgcn_mfma_f32_16x16x32_bf16(af[mi], bfr[ni], acc[mi][ni], 0, 0, 0); \
    asm volatile("s_waitcnt lgkmcnt(0)" ::: "memory"); \
    __builtin_amdgcn_s_barrier(); \
    if ((tt) + 3 < nst) STG((tt) + 3, b); }

  STG(0, 0); STG(1, 1); STG(2, 2);
  for (int tt = 0; tt < nst; tt += 3){
    STEP(0, tt); STEP(1, tt + 1); STEP(2, tt + 2);
  }
  #undef STEP
  #undef STG

  float bs[4];
  #pragma unroll
  for (int ni = 0; ni < 4; ++ni) bs[ni] = bias[bn + wc*64 + ni*16 + lr];
  #pragma unroll
  for (int mi = 0; mi < 4; ++mi){
    #pragma unroll
    for (int r2 = 0; r2 < 4; ++r2){
      int row = bm + wr*64 + mi*16 + lk*4 + r2;
      if constexpr (EPI == 0){
        int win = row / kN, n = row - win*kN;
        #pragma unroll
        for (int ni = 0; ni < 4; ++ni){
          int col = bn + wc*64 + ni*16 + lr;
          float v = acc[mi][ni][r2] + bs[ni];
          int which = col / kC; int cc = col - which*kC; int hd = cc >> 5, d = cc & 31;
          size_t plane = (size_t)(win*kHeads + hd) * 2048;
          if (which == 0)      o0[plane + n*32 + d] = f2b(v * kScale);
          else if (which == 1) o1[plane + n*32 + d] = f2b(v);
          else                 o2[plane + d*64 + n] = f2b(v);   // V transposed
        }
      } else if constexpr (EPI == 1){
        int win = row / kN, n = row - win*kN;
        int gw = aux + win;
        int b = gw >> 6, rem = gw & 63, wh = rem >> 3, ww = rem & 7;
        int ih = n / 7, iw = n - ih*7;
        int h0 = (wh*7 + ih + 3) % 56;
        int w0 = (ww*7 + iw + 3) % 56;
        size_t base = ((size_t)b*3136 + h0*56 + w0)*kC;
        #pragma unroll
        for (int ni = 0; ni < 4; ++ni){
          int col = bn + wc*64 + ni*16 + lr;
          fo[base + col] = acc[mi][ni][r2] + bs[ni] + res[base + col];
        }
      } else if constexpr (EPI == 2){
        size_t base = (size_t)row*kHid;
        #pragma unroll
        for (int ni = 0; ni < 4; ++ni){
          int col = bn + wc*64 + ni*16 + lr;
          float v = acc[mi][ni][r2] + bs[ni];
          v = 0.5f * v * (1.f + erff(v * 0.70710678118654752f));
          o0[base + col] = f2b(v);
        }
      } else {
        size_t base = (size_t)row*kC;
        #pragma unroll
        for (int ni = 0; ni < 4; ++ni){
          int col = bn + wc*64 + ni*16 + lr;
          fo[base + col] = acc[mi][ni][r2] + bs[ni] + res[base + col];
        }
      }
    }
  }
}

// ----------------------- MFMA window attention (v3) -----------------------
// 1 wave per (win,head). Q,K planes [64][32], V^T plane [32][64] (pad zeroed).
// S = QK^T via 16 mfma; softmax in-register (shfl over 16-lane row group);
// P(bf16) through per-wave XOR-swizzled LDS for the A-frag relayout; PV = 16 mfma.
__global__ __launch_bounds__(256) void attn_k(const bf* __restrict__ qq, const bf* __restrict__ kk,
                                              const bf* __restrict__ vt, const float* __restrict__ relb,
                                              bf* __restrict__ out){
  __shared__ float rbs[169*kHeads];          // 8112 B
  __shared__ u16 plds[4][64*64];             // 32 KiB (8 KiB / wave)
  int t = threadIdx.x, wv = t >> 6, l = t & 63;
  for (int i = t; i < 169*kHeads; i += 256) rbs[i] = relb[i];

  int bid = blockIdx.x*4 + wv, lw = bid / kHeads, h = bid - lw*kHeads;
  const u16* qp = (const u16*)qq + (size_t)bid*2048;
  const u16* kp = (const u16*)kk + (size_t)bid*2048;
  const u16* vp = (const u16*)vt + (size_t)bid*2048;
  int fr = l & 15, fk = l >> 4;              // frag row, k-group

  bf16x8 qf[4], kf[4];
  #pragma unroll
  for (int ti = 0; ti < 4; ++ti){
    qf[ti] = __builtin_bit_cast(bf16x8, *(const us8*)(qp + (ti*16 + fr)*32 + fk*8));
    kf[ti] = __builtin_bit_cast(bf16x8, *(const us8*)(kp + (ti*16 + fr)*32 + fk*8));
  }
  f32x4 s[4][4];
  #pragma unroll
  for (int i = 0; i < 4; ++i)
    #pragma unroll
    for (int j = 0; j < 4; ++j) s[i][j] = (f32x4){0.f,0.f,0.f,0.f};
  #pragma unroll
  for (int ti = 0; ti < 4; ++ti)
    #pragma unroll
    for (int tj = 0; tj < 4; ++tj)
      s[ti][tj] = __builtin_amdgcn_mfma_f32_16x16x32_bf16(qf[ti], kf[tj], s[ti][tj], 0, 0, 0);
  __syncthreads();                            // rbs ready

  // per-tj column info (col = key index j)
  int kh[4], kw[4], cvalid[4];
  #pragma unroll
  for (int tj = 0; tj < 4; ++tj){
    int c = tj*16 + fr;
    kh[tj] = c / 7; kw[tj] = c - kh[tj]*7; cvalid[tj] = c < kN;
  }
  // softmax per (ti,reg) row: bias+mask, rowmax/rowsum via shfl over fr-lanes
  #pragma unroll
  for (int ti = 0; ti < 4; ++ti){
    #pragma unroll
    for (int reg = 0; reg < 4; ++reg){
      int R = ti*16 + fk*4 + reg;
      int Rc = R < kN ? R : kN-1;
      int ih = Rc / 7, iw = Rc - ih*7;
      float v[4];
      #pragma unroll
      for (int tj = 0; tj < 4; ++tj){
        float b = rbs[((ih - kh[tj] + 6)*13 + (iw - kw[tj] + 6))*kHeads + h];
        v[tj] = cvalid[tj] ? s[ti][tj][reg] + b : -1e30f;
      }
      float m = fmaxf(fmaxf(v[0], v[1]), fmaxf(v[2], v[3]));
      #pragma unroll
      for (int msk = 1; msk < 16; msk <<= 1) m = fmaxf(m, __shfl_xor(m, msk));
      float e0 = __expf(v[0]-m), e1 = __expf(v[1]-m), e2 = __expf(v[2]-m), e3 = __expf(v[3]-m);
      float sum = (e0+e1) + (e2+e3);
      #pragma unroll
      for (int msk = 1; msk < 16; msk <<= 1) sum += __shfl_xor(sum, msk);
      float inv = 1.f / sum;
      s[ti][0][reg] = e0*inv; s[ti][1][reg] = e1*inv;
      s[ti][2][reg] = e2*inv; s[ti][3][reg] = e3*inv;
    }
  }
  // P -> LDS (bf16), XOR-swizzled 16B units: unit' = unit ^ (row&7)
  u16* P = plds[wv];
  #pragma unroll
  for (int ti = 0; ti < 4; ++ti)
    #pragma unroll
    for (int tj = 0; tj < 4; ++tj)
      #pragma unroll
      for (int reg = 0; reg < 4; ++reg){
        int R = ti*16 + fk*4 + reg, c = tj*16 + fr;
        P[R*64 + (((c>>3) ^ (R&7)) << 3) + (c&7)] = __builtin_bit_cast(u16, f2b(s[ti][tj][reg]));
      }
  // PV: O[64][32] = P[64][64] * V[64][32]  (B-frag = V^T rows)
  f32x4 o[4][2];
  #pragma unroll
  for (int i = 0; i < 4; ++i){ o[i][0] = (f32x4){0.f,0.f,0.f,0.f}; o[i][1] = (f32x4){0.f,0.f,0.f,0.f}; }
  #pragma unroll
  for (int ks = 0; ks < 2; ++ks){
    bf16x8 vf[2];
    #pragma unroll
    for (int tdj = 0; tdj < 2; ++tdj)
      vf[tdj] = __builtin_bit_cast(bf16x8, *(const us8*)(vp + (tdj*16 + fr)*64 + ks*32 + fk*8));
    #pragma unroll
    for (int ti = 0; ti < 4; ++ti){
      bf16x8 af = __builtin_bit_cast(bf16x8, *(const us8*)&P[(ti*16 + fr)*64 + (((ks*4 + fk) ^ (fr&7)) << 3)]);
      #pragma unroll
      for (int tdj = 0; tdj < 2; ++tdj)
        o[ti][tdj] = __builtin_amdgcn_mfma_f32_16x16x32_bf16(af, vf[tdj], o[ti][tdj], 0, 0, 0);
    }
  }
  // store (rows < 49 only)
  #pragma unroll
  for (int ti = 0; ti < 4; ++ti)
    #pragma unroll
    for (int reg = 0; reg < 4; ++reg){
      int R = ti*16 + fk*4 + reg;
      if (R < kN){
        bf* op = out + ((size_t)lw*kN + R)*kC + h*32;
        #pragma unroll
        for (int tdj = 0; tdj < 2; ++tdj)
          op[tdj*16 + fr] = f2b(o[ti][tdj][reg]);
      }
    }
}

extern "C" void kernel_launch(void* const* d_in, const int* in_sizes, int n_in,
                              void* d_out, int out_size, void* d_ws, size_t ws_size,
                              hipStream_t stream){
  (void)in_sizes; (void)n_in; (void)out_size; (void)ws_size;
  const float* x     = (const float*)d_in[0];
  const float* n1g   = (const float*)d_in[1];
  const float* n1b   = (const float*)d_in[2];
  const float* qkvw  = (const float*)d_in[3];
  const float* qkvb  = (const float*)d_in[4];
  const float* relb  = (const float*)d_in[5];
  const float* projw = (const float*)d_in[6];
  const float* projb = (const float*)d_in[7];
  const float* n2g   = (const float*)d_in[8];
  const float* n2b   = (const float*)d_in[9];
  const float* fc1w  = (const float*)d_in[10];
  const float* fc1b  = (const float*)d_in[11];
  const float* fc2w  = (const float*)d_in[12];
  const float* fc2b  = (const float*)d_in[13];
  float* out = (float*)d_out;

  char* w = (char*)d_ws;
  const size_t WINB  = 19267584;   // 25088*384*2
  const size_t BIGB  = 77070336;   // 25088*1536*2 (>= 3*kPlane*2 = 75.5MB)
  bf* winbuf = (bf*)w;
  bf* big    = (bf*)(w + WINB);
  bf* wts    = (bf*)(w + WINB + BIGB);
  bf* qkvwt  = wts;
  bf* projwt = qkvwt + 442368;
  bf* fc1wt  = projwt + 147456;
  bf* fc2wt  = fc1wt + 589824;
  bf* qb = big; bf* kb = big + (size_t)kPlane; bf* vb = big + 2*(size_t)kPlane;

  tr_k<<<dim3((442368+255)/256), 256, 0, stream>>>(qkvw,  qkvwt, 384, 1152);
  tr_k<<<dim3((147456+255)/256), 256, 0, stream>>>(projw, projwt, 384, 384);
  tr_k<<<dim3((589824+255)/256), 256, 0, stream>>>(fc1w,  fc1wt, 384, 1536);
  tr_k<<<dim3((589824+255)/256), 256, 0, stream>>>(fc2w,  fc2wt, 1536, 384);

  // zero V^T planes once per call (pads must be exact 0 for PV)
  hipMemsetAsync(vb, 0, (size_t)kPlane*2, stream);

  for (int c = 0; c < 4; ++c){
    int winbase = c * kChunkWins;
    ln_k<1><<<kChunkRows/4, 256, 0, stream>>>(x, n1g, n1b, winbuf, winbase);
    gemm_k<0><<<196*9, 256, 0, stream>>>(winbuf, qkvwt, qkvb, 384, 9,
                                         qb, kb, vb, nullptr, nullptr, 0);
    attn_k<<<kChunkWins*kHeads/4, 256, 0, stream>>>(qb, kb, vb, relb, winbuf);
    gemm_k<1><<<196*3, 256, 0, stream>>>(winbuf, projwt, projb, 384, 3,
                                         nullptr, nullptr, nullptr, out, x, winbase);
  }
  for (int c = 0; c < 4; ++c){
    float* xr = out + (size_t)c * kChunkRows * kC;
    ln_k<0><<<kChunkRows/4, 256, 0, stream>>>(xr, n2g, n2b, winbuf, 0);
    gemm_k<2><<<196*12, 256, 0, stream>>>(winbuf, fc1wt, fc1b, 384, 12,
                                          big, nullptr, nullptr, nullptr, nullptr, 0);
    gemm_k<3><<<196*3, 256, 0, stream>>>(big, fc2wt, fc2b, 1536, 3,
                                         nullptr, nullptr, nullptr, xr, xr, 0);
  }
}